// Round 1
// 302.152 us; speedup vs baseline: 1.0009x; 1.0009x over previous
//
#include <hip/hip_runtime.h>

// SpectralLayer reduction (algebra verified; fp32 buffers confirmed round 4):
//   out[:, :512]  = data[:, :512]                        (exact pass-through)
//   out[:, 512+n] = relu( d_n*data[:,512+n] + (1-d_n)*t_n ),
//       t = data[:, :512] @ W^T,  W[n][k] = base[512+n][k],  d = v^2 - v + 1
// Round 6: latency-bound fix. (1) Double-buffered LDS with 1-iter register
// prefetch so the global-load drain (forced by the compiler's vmcnt(0) before
// s_barrier) lands AFTER the tile's frag-reads + MFMAs instead of immediately.
// (2) XOR swizzle (chunk ^= (row>>1)&3, 16B-granular) kills the 8-way bank
// conflict on ds_read_b128 fragment reads (SQ_LDS_BANK_CONFLICT was 2.1M =
// 4x per-wave-read). (3) Pass-through copy moved after the epilogue so its
// traffic isn't drained by the k-loop's first barrier.

typedef float f32x4 __attribute__((ext_vector_type(4)));
typedef int   i32x4 __attribute__((ext_vector_type(4)));

#define DIMW   1024
#define HALFD  512
#define BM     128
#define BN     128
#define BK     32
#define NITER  16          // HALFD / BK

__device__ __forceinline__ unsigned short f2bf(float x) {
    union { float f; unsigned int i; } c;
    c.f = x;
    unsigned int r = c.i + 0x7FFFu + ((c.i >> 16) & 1u);  // round-nearest-even
    return (unsigned short)(r >> 16);
}
__device__ __forceinline__ unsigned int pack2(float a, float b) {
    return (unsigned int)f2bf(a) | ((unsigned int)f2bf(b) << 16);
}

// D(f32x4) += A(8 bf16 in 4 VGPRs) * B(8 bf16 in 4 VGPRs); C tied to D.
__device__ __forceinline__ void mfma_16x16x32_bf16(f32x4& d, const i32x4& a, const i32x4& b) {
    asm volatile("v_mfma_f32_16x16x32_bf16 %0, %1, %2, %0"
                 : "+v"(d)
                 : "v"(a), "v"(b));
}
// Hazard fence: VALU may not read an MFMA result for ~8 cycles.
__device__ __forceinline__ void acc_fence(f32x4& d) {
    asm volatile("s_nop 7\n\ts_nop 7" : "+v"(d));
}

__global__ __launch_bounds__(256, 3) void spectral_kernel(
    const float* __restrict__ data,
    const float* __restrict__ wsrc,   // base: W at rows [512,1024), cols [0,512)
    const float* __restrict__ td,
    const float* __restrict__ tdm,
    const float* __restrict__ ud,
    float* __restrict__ out)
{
    // Double-buffered, XOR-swizzled bf16 tiles. Row = 32 bf16 = 64 B = 4x16B
    // chunks; swizzled chunk = chunk ^ ((row>>1)&3). 16B granularity keeps
    // ds_read_b128 / 8B ds_write alignment; write phases (2 rows/quarter-wave)
    // stay conflict-free, read phases go 8-way -> 2-way (free, m136).
    __shared__ unsigned short As[2][BM * BK];
    __shared__ unsigned short Bs[2][BN * BK];
    __shared__ float dsh[BN];

    const int tid    = (int)threadIdx.x;
    const int lane   = tid & 63;
    const int wave   = tid >> 6;
    const int lane16 = lane & 15;
    const int quad   = lane >> 4;
    const int wm     = wave >> 1;            // 2x2 wave grid, 64x64 per wave
    const int wn     = wave & 1;
    const int rowBase = (int)blockIdx.x * BM;
    const int colBase = (int)blockIdx.y * BN;   // n in [0,512)

    // d[n] for this block's 128 output columns (diag entries at [512+n][512+n])
    if (tid < BN) {
        int j = HALFD + colBase + tid;
        size_t fi = (size_t)j * DIMW + j;
        dsh[tid] = td[fi] * tdm[fi] + ud[fi];
    }

    f32x4 acc[4][4];
    #pragma unroll
    for (int mi = 0; mi < 4; ++mi)
        #pragma unroll
        for (int ni = 0; ni < 4; ++ni)
            acc[mi][ni] = (f32x4){0.f, 0.f, 0.f, 0.f};

    float4 av[4], bv[4];

    // --- staging helpers (c = chunk id 0..1023: r = row, kc = k-element) ---
    auto LOADT = [&](int k0) {
        #pragma unroll
        for (int p = 0; p < 4; ++p) {
            int c  = p * 256 + tid;
            int r  = c >> 3;
            int kc = (c & 7) * 4;
            av[p] = *(const float4*)(data + (size_t)(rowBase + r) * DIMW + k0 + kc);
            bv[p] = *(const float4*)(wsrc + (size_t)(HALFD + colBase + r) * DIMW + k0 + kc);
        }
    };
    auto PACKW = [&](int buf) {
        #pragma unroll
        for (int p = 0; p < 4; ++p) {
            int c    = p * 256 + tid;
            int r    = c >> 3;
            int half = c & 7;                 // 4-element (8B) sub-chunk 0..7
            // swizzled: chunk (16B) = half>>1, XOR with (r>>1)&3
            int idx = r * BK + ((((half >> 1) ^ ((r >> 1) & 3)) << 3)) + (half & 1) * 4;
            uint2 ua, ub;
            ua.x = pack2(av[p].x, av[p].y);  ua.y = pack2(av[p].z, av[p].w);
            ub.x = pack2(bv[p].x, bv[p].y);  ub.y = pack2(bv[p].z, bv[p].w);
            *(uint2*)(&As[buf][idx]) = ua;
            *(uint2*)(&Bs[buf][idx]) = ub;
        }
    };

    // --- prologue: stage tile 0 ---
    LOADT(0);
    PACKW(0);
    __syncthreads();

    for (int it = 0; it < NITER; ++it) {
        const int cur = it & 1;

        // Issue next tile's global loads NOW; they drain at PACKW below,
        // after this tile's frag-reads + MFMAs (plus other waves' work).
        if (it + 1 < NITER) LOADT((it + 1) * BK);

        // Fragments: A[m=lane16][k=quad*8+j], B[n=lane16][k=quad*8+j]
        i32x4 a[4], b[4];
        #pragma unroll
        for (int mi = 0; mi < 4; ++mi) {
            int R = wm * 64 + mi * 16 + lane16;
            a[mi] = *(const i32x4*)(&As[cur][R * BK + ((quad ^ ((R >> 1) & 3)) << 3)]);
        }
        #pragma unroll
        for (int ni = 0; ni < 4; ++ni) {
            int R = wn * 64 + ni * 16 + lane16;
            b[ni] = *(const i32x4*)(&Bs[cur][R * BK + ((quad ^ ((R >> 1) & 3)) << 3)]);
        }

        #pragma unroll
        for (int mi = 0; mi < 4; ++mi)
            #pragma unroll
            for (int ni = 0; ni < 4; ++ni)
                mfma_16x16x32_bf16(acc[mi][ni], a[mi], b[ni]);

        __syncthreads();                       // WAR: all reads of buf[cur^1] done
        if (it + 1 < NITER) {
            PACKW(cur ^ 1);                    // vmcnt drain happens here
            __syncthreads();                   // RAW: buf[cur^1] ready for next iter
        }
    }

    #pragma unroll
    for (int mi = 0; mi < 4; ++mi)
        #pragma unroll
        for (int ni = 0; ni < 4; ++ni)
            acc_fence(acc[mi][ni]);

    // Epilogue. C/D layout: col(n) = lane&15, row(m) = quad*4 + reg. [m89 verified]
    #pragma unroll
    for (int mi = 0; mi < 4; ++mi) {
        int mBase = rowBase + wm * 64 + mi * 16 + quad * 4;
        #pragma unroll
        for (int ni = 0; ni < 4; ++ni) {
            int nloc = wn * 64 + ni * 16 + lane16;
            float dv = dsh[nloc];
            int col  = HALFD + colBase + nloc;
            #pragma unroll
            for (int r = 0; r < 4; ++r) {
                int row  = mBase + r;
                size_t gi = (size_t)row * DIMW + col;
                float u1 = data[gi];
                float v  = dv * u1 + (1.0f - dv) * acc[mi][ni][r];
                out[gi] = fmaxf(v, 0.0f);
            }
        }
    }

    // Fused pass-through copy: out[rowBase..+128, colBase..+128) = data[same].
    // Placed after the k-loop so its vmem traffic isn't drained by the loop's
    // barriers; no barrier needed (per-thread global ops only).
    {
        const float4* src = (const float4*)data;   // 256 float4 per row
        float4*       dst = (float4*)out;
        #pragma unroll
        for (int p = 0; p < 16; ++p) {
            int c  = p * 256 + tid;                // 4096 chunks: 128 rows x 32
            int r  = c >> 5;
            int cc = c & 31;
            size_t off = (size_t)(rowBase + r) * (DIMW / 4) + (colBase >> 2) + cc;
            dst[off] = src[off];
        }
    }
}

extern "C" void kernel_launch(void* const* d_in, const int* in_sizes, int n_in,
                              void* d_out, int out_size, void* d_ws, size_t ws_size,
                              hipStream_t stream) {
    // setup_inputs order: 0 data, 1 base, 2 base_mask, 3 eye, 4 trainable_diag,
    //                     5 trainable_diag_mask, 6 untrainable_diag, 7 mask1, 8 mask2
    const float* data = (const float*)d_in[0];
    const float* base = (const float*)d_in[1];
    const float* td   = (const float*)d_in[4];
    const float* tdm  = (const float*)d_in[5];
    const float* ud   = (const float*)d_in[6];
    float* out = (float*)d_out;

    dim3 grid(32768 / BM, HALFD / BN);   // 256 x 4 = 1024 blocks
    dim3 block(256, 1, 1);
    spectral_kernel<<<grid, block, 0, stream>>>(data, base, td, tdm, ud, out);
}